// Round 2
// baseline (798.773 us; speedup 1.0000x reference)
//
#include <hip/hip_runtime.h>
#include <math.h>

// ---------------------------------------------------------------------------
// LightAttention fp32 baseline.
//   B=8, C=16, S=512, N=512, V=128
// Pipeline (all batched over bc = b*C+c, 128 pairs):
//   1) buf[0:128]   = k_left[c]  @ x[bc]      (V x N)
//      buf[128:256] = v1_left[c] @ x[bc]
//      buf[256:384] = v2_w[c]    @ x[bc]
//   2) kmat = buf[0:128]   @ k_right[c]   (V x V)
//      v1   = buf[128:256] @ v1_right[c]  (V x V)
//   3) q = x @ wq[c]                       (S x V)
//   4) attn = softmax(q @ kmat^T)  in-place over q
//   5) v = v1 @ buf[256:384] -> overwrite buf[0:128]
//   6) out = x + attn @ v; fused per-channel sum/sumsq atomics
//   7) finalize scale/shift per channel
//   8) out = out*scale[c] + shift[c]
// Workspace: ~144 MiB fp32.
// ---------------------------------------------------------------------------

constexpr int Bb = 8, Cc = 16, Ss = 512, Nn = 512, Vv = 128;
constexpr int BC = Bb * Cc;                // 128
constexpr long X_BC   = (long)Ss * Nn;     // 262144
constexpr long BUF_BC = 384L * 512;        // 196608
constexpr long Q_BC   = (long)Ss * Vv;     // 65536
constexpr long K_BC   = (long)Vv * Vv;     // 16384

constexpr size_t OFF_BUF = 0;
constexpr size_t OFF_Q   = (size_t)BC * BUF_BC;           // 25,165,824
constexpr size_t OFF_K   = OFF_Q  + (size_t)BC * Q_BC;    // + 8,388,608
constexpr size_t OFF_V1  = OFF_K  + (size_t)BC * K_BC;    // + 2,097,152
constexpr size_t OFF_ST  = OFF_V1 + (size_t)BC * K_BC;    // + 2,097,152
// total floats = 37,748,800  (~144 MiB)

#define TILE 64
#define KST  16
#define ASTR 68   // padded LDS stride for transposed A tile (mult of 4, not mult of 32)

// 64x64 tile GEMM core: C += A(row-major, lda) @ B(row-major, ldb), K inner.
// 256 threads; thread (tx,ty) computes 4x4 micro-tile.
__device__ __forceinline__ void gemm64x64(const float* __restrict__ A, int lda,
                                          const float* __restrict__ Bp, int ldb,
                                          int K, float (&acc)[4][4],
                                          float (*As)[ASTR], float (*Bs)[TILE])
{
    const int tid  = threadIdx.x;
    const int tx   = tid & 15, ty = tid >> 4;
    const int la_r = tid >> 2,        la_k = (tid & 3) * 4;
    const int lb_k = tid >> 4,        lb_n = (tid & 15) * 4;

    for (int k0 = 0; k0 < K; k0 += KST) {
        float4 a4 = *reinterpret_cast<const float4*>(A + (long)la_r * lda + k0 + la_k);
        float4 b4 = *reinterpret_cast<const float4*>(Bp + (long)(k0 + lb_k) * ldb + lb_n);
        __syncthreads();
        As[la_k + 0][la_r] = a4.x;
        As[la_k + 1][la_r] = a4.y;
        As[la_k + 2][la_r] = a4.z;
        As[la_k + 3][la_r] = a4.w;
        *reinterpret_cast<float4*>(&Bs[lb_k][lb_n]) = b4;
        __syncthreads();
#pragma unroll
        for (int kk = 0; kk < KST; ++kk) {
            float a0 = As[kk][ty * 4 + 0];
            float a1 = As[kk][ty * 4 + 1];
            float a2 = As[kk][ty * 4 + 2];
            float a3 = As[kk][ty * 4 + 3];
            float b0 = Bs[kk][tx * 4 + 0];
            float b1 = Bs[kk][tx * 4 + 1];
            float b2 = Bs[kk][tx * 4 + 2];
            float b3 = Bs[kk][tx * 4 + 3];
            acc[0][0] += a0 * b0; acc[0][1] += a0 * b1; acc[0][2] += a0 * b2; acc[0][3] += a0 * b3;
            acc[1][0] += a1 * b0; acc[1][1] += a1 * b1; acc[1][2] += a1 * b2; acc[1][3] += a1 * b3;
            acc[2][0] += a2 * b0; acc[2][1] += a2 * b1; acc[2][2] += a2 * b2; acc[2][3] += a2 * b3;
            acc[3][0] += a3 * b0; acc[3][1] += a3 * b1; acc[3][2] += a3 * b2; acc[3][3] += a3 * b3;
        }
    }
}

// ---- 0) zero the stats buffer ---------------------------------------------
__global__ void k_zero(float* __restrict__ stats)
{
    if (threadIdx.x < 64) stats[threadIdx.x] = 0.f;
}

// ---- 1) fused left GEMMs: buf = {k_left, v1_left, v2_w}[c] @ x[bc] --------
__global__ __launch_bounds__(256) void k_wx(const float* __restrict__ kl,
                                            const float* __restrict__ v1l,
                                            const float* __restrict__ v2w,
                                            const float* __restrict__ x,
                                            float* __restrict__ buf)
{
    __shared__ float As[KST][ASTR];
    __shared__ float Bs[KST][TILE];
    const int bc = blockIdx.z, c = bc & (Cc - 1);
    const int m0 = blockIdx.y * TILE, n0 = blockIdx.x * TILE;
    const int which = m0 >> 7, rin = m0 & 127;
    const float* W = (which == 0) ? kl : (which == 1) ? v1l : v2w;
    const float* A  = W + (long)c * Vv * Ss + (long)rin * Ss;
    const float* Bp = x + (long)bc * X_BC + n0;
    float acc[4][4] = {};
    gemm64x64(A, Ss, Bp, Nn, Ss, acc, As, Bs);
    float* Cp = buf + (long)bc * BUF_BC + (long)m0 * 512 + n0;
    const int tx = threadIdx.x & 15, ty = threadIdx.x >> 4;
#pragma unroll
    for (int i = 0; i < 4; ++i)
#pragma unroll
        for (int j = 0; j < 4; ++j)
            Cp[(long)(ty * 4 + i) * 512 + tx * 4 + j] = acc[i][j];
}

// ---- 2) right GEMMs: kmat = kx @ k_right ; v1 = v1x @ v1_right ------------
__global__ __launch_bounds__(256) void k_kr(const float* __restrict__ buf,
                                            const float* __restrict__ kr,
                                            const float* __restrict__ v1r,
                                            float* __restrict__ kout,
                                            float* __restrict__ v1out)
{
    __shared__ float As[KST][ASTR];
    __shared__ float Bs[KST][TILE];
    const int zz = blockIdx.z;
    const int bc = zz & 127, sel = zz >> 7, c = bc & (Cc - 1);
    const int m0 = blockIdx.y * TILE, n0 = blockIdx.x * TILE;
    const float* A  = buf + (long)bc * BUF_BC + (long)sel * 128 * 512 + (long)m0 * 512;
    const float* Bp = (sel ? v1r : kr) + (long)c * Nn * Vv + n0;
    float acc[4][4] = {};
    gemm64x64(A, 512, Bp, Vv, 512, acc, As, Bs);
    float* Cp = (sel ? v1out : kout) + (long)bc * K_BC + (long)m0 * Vv + n0;
    const int tx = threadIdx.x & 15, ty = threadIdx.x >> 4;
#pragma unroll
    for (int i = 0; i < 4; ++i)
#pragma unroll
        for (int j = 0; j < 4; ++j)
            Cp[(long)(ty * 4 + i) * Vv + tx * 4 + j] = acc[i][j];
}

// ---- 3) q = x @ wq --------------------------------------------------------
__global__ __launch_bounds__(256) void k_q(const float* __restrict__ x,
                                           const float* __restrict__ wq,
                                           float* __restrict__ q)
{
    __shared__ float As[KST][ASTR];
    __shared__ float Bs[KST][TILE];
    const int bc = blockIdx.z, c = bc & (Cc - 1);
    const int m0 = blockIdx.y * TILE, n0 = blockIdx.x * TILE;
    const float* A  = x + (long)bc * X_BC + (long)m0 * 512;
    const float* Bp = wq + (long)c * Nn * Vv + n0;
    float acc[4][4] = {};
    gemm64x64(A, 512, Bp, Vv, 512, acc, As, Bs);
    float* Cp = q + (long)bc * Q_BC + (long)m0 * Vv + n0;
    const int tx = threadIdx.x & 15, ty = threadIdx.x >> 4;
#pragma unroll
    for (int i = 0; i < 4; ++i)
#pragma unroll
        for (int j = 0; j < 4; ++j)
            Cp[(long)(ty * 4 + i) * Vv + tx * 4 + j] = acc[i][j];
}

// ---- 4) attn = softmax(q @ kmat^T), in-place over q -----------------------
// Block: 64 s-rows x full 128 w-cols. 256 thr, each 4 rows x 8 cols.
__global__ __launch_bounds__(256) void k_attn(float* __restrict__ q,
                                              const float* __restrict__ kmat)
{
    __shared__ float As[KST][ASTR];
    __shared__ float Bs[KST][132];
    const int bc = blockIdx.z;
    const int m0 = blockIdx.y * TILE;
    float* qb = q + (long)bc * Q_BC + (long)m0 * Vv;
    const float* kb = kmat + (long)bc * K_BC;
    const int tid = threadIdx.x;
    const int tx = tid & 15, ty = tid >> 4;           // cols tx*8..+7, rows ty*4..+3
    const int la_r = tid >> 2, la_k = (tid & 3) * 4;  // A loads
    const int lb_n = tid >> 1, lb_k = (tid & 1) * 8;  // B^T loads (k rows)

    float acc[4][8] = {};
    for (int k0 = 0; k0 < 128; k0 += KST) {
        float4 a4  = *reinterpret_cast<const float4*>(qb + (long)la_r * Vv + k0 + la_k);
        float4 b4a = *reinterpret_cast<const float4*>(kb + (long)lb_n * Vv + k0 + lb_k);
        float4 b4b = *reinterpret_cast<const float4*>(kb + (long)lb_n * Vv + k0 + lb_k + 4);
        __syncthreads();
        As[la_k + 0][la_r] = a4.x;
        As[la_k + 1][la_r] = a4.y;
        As[la_k + 2][la_r] = a4.z;
        As[la_k + 3][la_r] = a4.w;
        Bs[lb_k + 0][lb_n] = b4a.x;
        Bs[lb_k + 1][lb_n] = b4a.y;
        Bs[lb_k + 2][lb_n] = b4a.z;
        Bs[lb_k + 3][lb_n] = b4a.w;
        Bs[lb_k + 4][lb_n] = b4b.x;
        Bs[lb_k + 5][lb_n] = b4b.y;
        Bs[lb_k + 6][lb_n] = b4b.z;
        Bs[lb_k + 7][lb_n] = b4b.w;
        __syncthreads();
#pragma unroll
        for (int kk = 0; kk < KST; ++kk) {
            float a[4], b[8];
#pragma unroll
            for (int i = 0; i < 4; ++i) a[i] = As[kk][ty * 4 + i];
#pragma unroll
            for (int j = 0; j < 8; ++j) b[j] = Bs[kk][tx * 8 + j];
#pragma unroll
            for (int i = 0; i < 4; ++i)
#pragma unroll
                for (int j = 0; j < 8; ++j) acc[i][j] += a[i] * b[j];
        }
    }
    // row softmax over 128 cols: 16 contiguous lanes share a row (8 cols each)
#pragma unroll
    for (int i = 0; i < 4; ++i) {
        float m = -1e30f;
#pragma unroll
        for (int j = 0; j < 8; ++j) m = fmaxf(m, acc[i][j]);
#pragma unroll
        for (int d = 8; d >= 1; d >>= 1) m = fmaxf(m, __shfl_xor(m, d));
        float s = 0.f;
#pragma unroll
        for (int j = 0; j < 8; ++j) { acc[i][j] = __expf(acc[i][j] - m); s += acc[i][j]; }
#pragma unroll
        for (int d = 8; d >= 1; d >>= 1) s += __shfl_xor(s, d);
        float inv = 1.f / s;
#pragma unroll
        for (int j = 0; j < 8; ++j) acc[i][j] *= inv;
    }
    // all q reads finished before the last store-barrier of the K-loop
#pragma unroll
    for (int i = 0; i < 4; ++i)
#pragma unroll
        for (int j = 0; j < 8; ++j)
            qb[(long)(ty * 4 + i) * Vv + tx * 8 + j] = acc[i][j];
}

// ---- 5) v = v1 @ v2; overwrite buf rows 0..127 ----------------------------
__global__ __launch_bounds__(256) void k_v(const float* __restrict__ v1,
                                           float* __restrict__ buf)
{
    __shared__ float As[KST][ASTR];
    __shared__ float Bs[KST][TILE];
    const int bc = blockIdx.z;
    const int m0 = blockIdx.y * TILE, n0 = blockIdx.x * TILE;
    const float* A  = v1 + (long)bc * K_BC + (long)m0 * Vv;
    const float* Bp = buf + (long)bc * BUF_BC + 256L * 512 + n0;
    float acc[4][4] = {};
    gemm64x64(A, Vv, Bp, 512, Vv, acc, As, Bs);
    float* Cp = buf + (long)bc * BUF_BC + (long)m0 * 512 + n0;
    const int tx = threadIdx.x & 15, ty = threadIdx.x >> 4;
#pragma unroll
    for (int i = 0; i < 4; ++i)
#pragma unroll
        for (int j = 0; j < 4; ++j)
            Cp[(long)(ty * 4 + i) * 512 + tx * 4 + j] = acc[i][j];
}

// ---- 6) out = x + attn @ v; fused per-channel sum/sumsq -------------------
__global__ __launch_bounds__(256) void k_y(const float* __restrict__ attn,
                                           const float* __restrict__ buf,
                                           const float* __restrict__ x,
                                           float* __restrict__ out,
                                           float* __restrict__ stats)
{
    __shared__ float As[KST][ASTR];
    __shared__ float Bs[KST][TILE];
    __shared__ float r1[4], r2[4];
    const int bc = blockIdx.z, c = bc & (Cc - 1);
    const int m0 = blockIdx.y * TILE, n0 = blockIdx.x * TILE;
    const float* A  = attn + (long)bc * Q_BC + (long)m0 * Vv;
    const float* Bp = buf + (long)bc * BUF_BC + n0;   // v rows 0..127
    float acc[4][4] = {};
    gemm64x64(A, Vv, Bp, 512, Vv, acc, As, Bs);

    const float* xb = x + (long)bc * X_BC + (long)m0 * 512 + n0;
    float* ob       = out + (long)bc * X_BC + (long)m0 * 512 + n0;
    const int tx = threadIdx.x & 15, ty = threadIdx.x >> 4;
    float lsum = 0.f, lss = 0.f;
#pragma unroll
    for (int i = 0; i < 4; ++i)
#pragma unroll
        for (int j = 0; j < 4; ++j) {
            const long off = (long)(ty * 4 + i) * 512 + tx * 4 + j;
            float yv = xb[off] + acc[i][j];
            ob[off] = yv;
            lsum += yv;
            lss  += yv * yv;
        }
#pragma unroll
    for (int d = 32; d >= 1; d >>= 1) {
        lsum += __shfl_xor(lsum, d);
        lss  += __shfl_xor(lss, d);
    }
    const int wid = threadIdx.x >> 6, lane = threadIdx.x & 63;
    if (lane == 0) { r1[wid] = lsum; r2[wid] = lss; }
    __syncthreads();
    if (threadIdx.x == 0) {
        float s  = r1[0] + r1[1] + r1[2] + r1[3];
        float ss = r2[0] + r2[1] + r2[2] + r2[3];
        atomicAdd(&stats[c * 2 + 0], s);
        atomicAdd(&stats[c * 2 + 1], ss);
    }
}

// ---- 7) finalize per-channel scale/shift ----------------------------------
__global__ void k_fin(float* __restrict__ stats,
                      const float* __restrict__ gamma,
                      const float* __restrict__ beta)
{
    const int c = threadIdx.x;
    if (c < Cc) {
        const float cnt  = (float)((long)Bb * Ss * Nn);   // 2,097,152
        const float mean = stats[c * 2 + 0] / cnt;
        const float var  = stats[c * 2 + 1] / cnt - mean * mean;
        const float rstd = rsqrtf(var + 1e-5f);
        const float sc   = rstd * gamma[c];
        stats[32 + c * 2 + 0] = sc;
        stats[32 + c * 2 + 1] = beta[c] - mean * sc;
    }
}

// ---- 8) out = out*scale[c] + shift[c] (in place, float4) ------------------
__global__ __launch_bounds__(256) void k_norm(float* __restrict__ out,
                                              const float* __restrict__ stats)
{
    const long tot = (long)BC * X_BC / 4;   // 8,388,608 float4s
    for (long i = (long)blockIdx.x * blockDim.x + threadIdx.x; i < tot;
         i += (long)gridDim.x * blockDim.x) {
        const long e = i * 4;
        const int c  = (int)(e >> 18) & (Cc - 1);
        const float sc = stats[32 + c * 2 + 0];
        const float sh = stats[32 + c * 2 + 1];
        float4 v = reinterpret_cast<float4*>(out)[i];
        v.x = v.x * sc + sh;
        v.y = v.y * sc + sh;
        v.z = v.z * sc + sh;
        v.w = v.w * sc + sh;
        reinterpret_cast<float4*>(out)[i] = v;
    }
}

extern "C" void kernel_launch(void* const* d_in, const int* in_sizes, int n_in,
                              void* d_out, int out_size, void* d_ws, size_t ws_size,
                              hipStream_t stream)
{
    (void)in_sizes; (void)n_in; (void)out_size; (void)ws_size;
    const float* x     = (const float*)d_in[0];
    const float* wq    = (const float*)d_in[1];
    const float* kl    = (const float*)d_in[2];
    const float* kr    = (const float*)d_in[3];
    const float* v1l   = (const float*)d_in[4];
    const float* v1r   = (const float*)d_in[5];
    const float* v2w   = (const float*)d_in[6];
    const float* gamma = (const float*)d_in[7];
    const float* beta  = (const float*)d_in[8];
    float* out = (float*)d_out;
    float* ws  = (float*)d_ws;

    float* buf   = ws + OFF_BUF;
    float* q     = ws + OFF_Q;
    float* kmat  = ws + OFF_K;
    float* v1    = ws + OFF_V1;
    float* stats = ws + OFF_ST;

    hipLaunchKernelGGL(k_zero, dim3(1), dim3(64), 0, stream, stats);
    hipLaunchKernelGGL(k_wx,   dim3(8, 6, 128), dim3(256), 0, stream, kl, v1l, v2w, x, buf);
    hipLaunchKernelGGL(k_kr,   dim3(2, 2, 256), dim3(256), 0, stream, buf, kr, v1r, kmat, v1);
    hipLaunchKernelGGL(k_q,    dim3(2, 8, 128), dim3(256), 0, stream, x, wq, q);
    hipLaunchKernelGGL(k_attn, dim3(1, 8, 128), dim3(256), 0, stream, q, kmat);
    hipLaunchKernelGGL(k_v,    dim3(8, 2, 128), dim3(256), 0, stream, v1, buf);
    hipLaunchKernelGGL(k_y,    dim3(8, 8, 128), dim3(256), 0, stream, q, buf, x, out, stats);
    hipLaunchKernelGGL(k_fin,  dim3(1), dim3(64), 0, stream, stats, gamma, beta);
    hipLaunchKernelGGL(k_norm, dim3(2048), dim3(256), 0, stream, out, stats);
}

// Round 3
// 519.006 us; speedup vs baseline: 1.5390x; 1.5390x over previous
//
#include <hip/hip_runtime.h>
#include <math.h>

// ---------------------------------------------------------------------------
// LightAttention, bf16-MFMA pipeline.  B=8,C=16,S=512,N=512,V=128, bc=128.
// All GEMM operands stored [dim][k] row-major bf16 (k-contiguous) so both
// MFMA A- and B-fragments are 16B-contiguous LDS reads (XOR-swizzled).
// Residual add, softmax math, and batch-norm stats remain fp32.
//
//  conv:  x -> xb (bf16 [s][n]) + xt (bf16 [n][s]);  wq,kr,v1r -> transposed
//         bf16 [v][n]; kl,v1l,v2w -> bf16 straight.
//  k_wx:  {kl,v1l,v2w}@x^T per bc -> buf(kx,v1x [w][n]) ; v2 stored as v2t[n][v]
//  k_kr:  kx@krt -> kmat[w][v] ; v1x@v1rt -> v1m[a][b]
//  k_q :  x@wqt -> q[s][v]
//  k_at:  softmax(q@kmat^T) -> attn[s][w]  (wave-local softmax, fp32)
//  k_v :  v2t@v1m^T-form -> vt[n][w]   (= (v1@v2)^T, no extra transposes)
//  k_y :  out = x + attn@vt^T (fp32) + fused per-channel sum/sumsq atomics
//  k_fin/k_norm: batch-norm finalize + apply.
// ---------------------------------------------------------------------------

typedef short  bf16x8 __attribute__((ext_vector_type(8)));
typedef float  f32x4  __attribute__((ext_vector_type(4)));

__device__ __forceinline__ unsigned short f2bf(float f) {
    union { float f; unsigned u; } v; v.f = f;
    return (unsigned short)((v.u + 0x7FFF + ((v.u >> 16) & 1)) >> 16);
}

// ---- workspace layout (bytes) ---------------------------------------------
constexpr size_t OB_XB   = 0;                          // 128*512*512*2 = 64 MiB
constexpr size_t OB_XT   = OB_XB  + 67108864;          // 64 MiB
constexpr size_t OB_KLB  = OB_XT  + 67108864;          // 2 MiB each
constexpr size_t OB_V1LB = OB_KLB + 2097152;
constexpr size_t OB_V2WB = OB_V1LB+ 2097152;
constexpr size_t OB_WQT  = OB_V2WB+ 2097152;
constexpr size_t OB_KRT  = OB_WQT + 2097152;
constexpr size_t OB_V1RT = OB_KRT + 2097152;
constexpr size_t OB_BUF  = OB_V1RT+ 2097152;           // 128*256*512*2 = 32 MiB
constexpr size_t OB_V2T  = OB_BUF + 33554432;          // 128*512*128*2 = 16 MiB
constexpr size_t OB_KM   = OB_V2T + 16777216;          // 4 MiB
constexpr size_t OB_V1M  = OB_KM  + 4194304;           // 4 MiB
constexpr size_t OB_Q    = OB_V1M + 4194304;           // 16 MiB
constexpr size_t OB_ATT  = OB_Q   + 16777216;          // 16 MiB
constexpr size_t OB_VT   = OB_ATT + 16777216;          // 16 MiB
constexpr size_t OB_ST   = OB_VT  + 16777216;          // 256 B stats
// total ~244 MiB

// ---------------------------------------------------------------------------
// MFMA tile core. Tile = MT x 128 (MT=128: 4 waves 2x2; MT=256: 4 waves
// stacked, each owning 64 rows x full 128 cols). BK=64, single LDS buffer,
// reg-staged 16B loads with next-tile prefetch, XOR-swizzled LDS (2-way max).
// A: [MT][K] bf16 row-major (ldaB bytes/row); B: [128][K] bf16 row-major.
// ---------------------------------------------------------------------------
template<int NSTEPS, int MT>
__device__ __forceinline__ void mmcore(const char* __restrict__ Ab, int ldaB,
                                       const char* __restrict__ Bb, int ldbB,
                                       f32x4 (&acc)[4][(MT == 128) ? 4 : 8])
{
    constexpr int WNF = (MT == 128) ? 4 : 8;
    constexpr int AR  = MT / 32;                  // int4 staging regs for A
    __shared__ __align__(16) unsigned char smA[MT * 128];
    __shared__ __align__(16) unsigned char smB[128 * 128];
    const int tid = threadIdx.x;
    const int w = tid >> 6, l = tid & 63, g = l >> 4, lr = l & 15;
    const int wm = (MT == 128) ? (w >> 1) * 64 : w * 64;
    const int wn = (MT == 128) ? (w & 1) * 64 : 0;

    int4 ra[AR], rb[4];
#pragma unroll
    for (int r = 0; r < AR; ++r) { int qq = tid + 256 * r; int row = qq >> 3, c = qq & 7;
        ra[r] = *(const int4*)(Ab + (size_t)row * ldaB + c * 16); }
#pragma unroll
    for (int r = 0; r < 4; ++r)  { int qq = tid + 256 * r; int row = qq >> 3, c = qq & 7;
        rb[r] = *(const int4*)(Bb + (size_t)row * ldbB + c * 16); }

#pragma unroll 1
    for (int t = 0; t < NSTEPS; ++t) {
#pragma unroll
        for (int r = 0; r < AR; ++r) { int qq = tid + 256 * r; int row = qq >> 3, c = qq & 7;
            *(int4*)(smA + row * 128 + ((c ^ (row & 7)) * 16)) = ra[r]; }
#pragma unroll
        for (int r = 0; r < 4; ++r)  { int qq = tid + 256 * r; int row = qq >> 3, c = qq & 7;
            *(int4*)(smB + row * 128 + ((c ^ (row & 7)) * 16)) = rb[r]; }
        __syncthreads();
        if (t + 1 < NSTEPS) {                     // issue next-tile loads early
            const char* An = Ab + (size_t)(t + 1) * 128;
            const char* Bn = Bb + (size_t)(t + 1) * 128;
#pragma unroll
            for (int r = 0; r < AR; ++r) { int qq = tid + 256 * r; int row = qq >> 3, c = qq & 7;
                ra[r] = *(const int4*)(An + (size_t)row * ldaB + c * 16); }
#pragma unroll
            for (int r = 0; r < 4; ++r)  { int qq = tid + 256 * r; int row = qq >> 3, c = qq & 7;
                rb[r] = *(const int4*)(Bn + (size_t)row * ldbB + c * 16); }
        }
#pragma unroll
        for (int ks = 0; ks < 2; ++ks) {
            bf16x8 av[4], bv[WNF];
            const int ch = ks * 4 + g;
#pragma unroll
            for (int i = 0; i < 4; ++i) { int rw = wm + i * 16 + lr;
                av[i] = *(const bf16x8*)(smA + rw * 128 + ((ch ^ (rw & 7)) * 16)); }
#pragma unroll
            for (int j = 0; j < WNF; ++j) { int rw = wn + j * 16 + lr;
                bv[j] = *(const bf16x8*)(smB + rw * 128 + ((ch ^ (rw & 7)) * 16)); }
#pragma unroll
            for (int i = 0; i < 4; ++i)
#pragma unroll
                for (int j = 0; j < WNF; ++j)
                    acc[i][j] = __builtin_amdgcn_mfma_f32_16x16x32_bf16(av[i], bv[j], acc[i][j], 0, 0, 0);
        }
        __syncthreads();
    }
}

// ---- conversion kernels ---------------------------------------------------
__global__ __launch_bounds__(256) void kcvt(const float* __restrict__ src,
                                            unsigned short* __restrict__ dst, int n4)
{
    int i = blockIdx.x * 256 + threadIdx.x;
    const int stride = gridDim.x * 256;
    for (; i < n4; i += stride) {
        float4 v = ((const float4*)src)[i];
        ((ushort4*)dst)[i] = make_ushort4(f2bf(v.x), f2bf(v.y), f2bf(v.z), f2bf(v.w));
    }
}

// x[bc][s][n] fp32 -> xb bf16 straight + xt bf16 transposed [n][s]
__global__ __launch_bounds__(256) void ktransx(const float* __restrict__ x,
                                               unsigned short* __restrict__ xb,
                                               unsigned short* __restrict__ xt)
{
    __shared__ float tl[64][65];
    const int bc = blockIdx.z;
    const int r0 = blockIdx.y * 64, c0 = blockIdx.x * 64;
    const float* src = x + (size_t)bc * 262144;
    const int tid = threadIdx.x, rr = tid >> 4, cc = (tid & 15) * 4;
#pragma unroll
    for (int rep = 0; rep < 4; ++rep) {
        int row = rep * 16 + rr;
        float4 v = *(const float4*)(src + (size_t)(r0 + row) * 512 + c0 + cc);
        *(ushort4*)(xb + (size_t)bc * 262144 + (size_t)(r0 + row) * 512 + c0 + cc) =
            make_ushort4(f2bf(v.x), f2bf(v.y), f2bf(v.z), f2bf(v.w));
        tl[cc + 0][row] = v.x; tl[cc + 1][row] = v.y; tl[cc + 2][row] = v.z; tl[cc + 3][row] = v.w;
    }
    __syncthreads();
#pragma unroll
    for (int rep = 0; rep < 4; ++rep) {
        int crow = rep * 16 + rr;
        *(ushort4*)(xt + (size_t)bc * 262144 + (size_t)(c0 + crow) * 512 + r0 + cc) =
            make_ushort4(f2bf(tl[crow][cc]), f2bf(tl[crow][cc + 1]),
                         f2bf(tl[crow][cc + 2]), f2bf(tl[crow][cc + 3]));
    }
}

// w[c][512][128] fp32 -> dst bf16 transposed [c][128][512]
__global__ __launch_bounds__(256) void ktransw(const float* __restrict__ src,
                                               unsigned short* __restrict__ dst)
{
    __shared__ float tl[64][65];
    const int p = blockIdx.z;
    const int r0 = blockIdx.y * 64, c0 = blockIdx.x * 64;
    const float* s = src + (size_t)p * 65536;
    unsigned short* d = dst + (size_t)p * 65536;
    const int tid = threadIdx.x, rr = tid >> 4, cc = (tid & 15) * 4;
#pragma unroll
    for (int rep = 0; rep < 4; ++rep) {
        int row = rep * 16 + rr;
        float4 v = *(const float4*)(s + (size_t)(r0 + row) * 128 + c0 + cc);
        tl[cc + 0][row] = v.x; tl[cc + 1][row] = v.y; tl[cc + 2][row] = v.z; tl[cc + 3][row] = v.w;
    }
    __syncthreads();
#pragma unroll
    for (int rep = 0; rep < 4; ++rep) {
        int crow = rep * 16 + rr;
        *(ushort4*)(d + (size_t)(c0 + crow) * 512 + r0 + cc) =
            make_ushort4(f2bf(tl[crow][cc]), f2bf(tl[crow][cc + 1]),
                         f2bf(tl[crow][cc + 2]), f2bf(tl[crow][cc + 3]));
    }
}

__global__ void k_zero(float* __restrict__ stats)
{
    if (threadIdx.x < 64) stats[threadIdx.x] = 0.f;
}

// ---- GEMM kernels ---------------------------------------------------------
__global__ __launch_bounds__(256) void k_wx(const unsigned short* __restrict__ klb,
                                            const unsigned short* __restrict__ v1lb,
                                            const unsigned short* __restrict__ v2wb,
                                            const unsigned short* __restrict__ xt,
                                            unsigned short* __restrict__ bufb,
                                            unsigned short* __restrict__ v2t)
{
    const int bc = blockIdx.z, c = bc & 15;
    const int mt = blockIdx.y, n0 = blockIdx.x * 128;
    const unsigned short* W = (mt == 0) ? klb : (mt == 1) ? v1lb : v2wb;
    f32x4 acc[4][4] = {};
    mmcore<8, 128>((const char*)(W + (size_t)c * 65536), 1024,
                   (const char*)(xt + (size_t)bc * 262144 + (size_t)n0 * 512), 1024, acc);
    const int tid = threadIdx.x, w = tid >> 6, l = tid & 63, g = l >> 4, lr = l & 15;
    const int wm = (w >> 1) * 64, wn = (w & 1) * 64;
    if (mt < 2) {
        unsigned short* out = bufb + (size_t)bc * 131072 + (size_t)mt * 65536;
#pragma unroll
        for (int i = 0; i < 4; ++i)
#pragma unroll
            for (int j = 0; j < 4; ++j)
#pragma unroll
                for (int r = 0; r < 4; ++r)
                    out[(size_t)(wm + i * 16 + g * 4 + r) * 512 + n0 + wn + j * 16 + lr] = f2bf(acc[i][j][r]);
    } else {
        unsigned short* out = v2t + (size_t)bc * 65536;
#pragma unroll
        for (int i = 0; i < 4; ++i)
#pragma unroll
            for (int j = 0; j < 4; ++j) {
                int v = wm + i * 16 + g * 4, nn = n0 + wn + j * 16 + lr;
                *(ushort4*)(out + (size_t)nn * 128 + v) =
                    make_ushort4(f2bf(acc[i][j][0]), f2bf(acc[i][j][1]), f2bf(acc[i][j][2]), f2bf(acc[i][j][3]));
            }
    }
}

__global__ __launch_bounds__(256) void k_kr(const unsigned short* __restrict__ bufb,
                                            const unsigned short* __restrict__ krt,
                                            const unsigned short* __restrict__ v1rt,
                                            unsigned short* __restrict__ kmat,
                                            unsigned short* __restrict__ v1m)
{
    const int bc = blockIdx.z, c = bc & 15, mt = blockIdx.y;
    f32x4 acc[4][4] = {};
    mmcore<8, 128>((const char*)(bufb + (size_t)bc * 131072 + (size_t)mt * 65536), 1024,
                   (const char*)((mt ? v1rt : krt) + (size_t)c * 65536), 1024, acc);
    unsigned short* out = (mt ? v1m : kmat) + (size_t)bc * 16384;
    const int tid = threadIdx.x, w = tid >> 6, l = tid & 63, g = l >> 4, lr = l & 15;
    const int wm = (w >> 1) * 64, wn = (w & 1) * 64;
#pragma unroll
    for (int i = 0; i < 4; ++i)
#pragma unroll
        for (int j = 0; j < 4; ++j)
#pragma unroll
            for (int r = 0; r < 4; ++r)
                out[(size_t)(wm + i * 16 + g * 4 + r) * 128 + wn + j * 16 + lr] = f2bf(acc[i][j][r]);
}

__global__ __launch_bounds__(256) void k_q(const unsigned short* __restrict__ xb,
                                           const unsigned short* __restrict__ wqt,
                                           unsigned short* __restrict__ q)
{
    const int bc = blockIdx.z, c = bc & 15, mt = blockIdx.y;
    f32x4 acc[4][4] = {};
    mmcore<8, 128>((const char*)(xb + (size_t)bc * 262144 + (size_t)mt * 65536), 1024,
                   (const char*)(wqt + (size_t)c * 65536), 1024, acc);
    unsigned short* out = q + (size_t)bc * 65536 + (size_t)mt * 16384;
    const int tid = threadIdx.x, w = tid >> 6, l = tid & 63, g = l >> 4, lr = l & 15;
    const int wm = (w >> 1) * 64, wn = (w & 1) * 64;
#pragma unroll
    for (int i = 0; i < 4; ++i)
#pragma unroll
        for (int j = 0; j < 4; ++j)
#pragma unroll
            for (int r = 0; r < 4; ++r)
                out[(size_t)(wm + i * 16 + g * 4 + r) * 128 + wn + j * 16 + lr] = f2bf(acc[i][j][r]);
}

// attn = softmax(q @ kmat^T): MT=256, each wave owns 64 rows x all 128 cols.
__global__ __launch_bounds__(256) void k_at(const unsigned short* __restrict__ q,
                                            const unsigned short* __restrict__ kmat,
                                            unsigned short* __restrict__ attn)
{
    const int bc = blockIdx.z, mt = blockIdx.y;
    f32x4 acc[4][8] = {};
    mmcore<2, 256>((const char*)(q + (size_t)bc * 65536 + (size_t)mt * 32768), 256,
                   (const char*)(kmat + (size_t)bc * 16384), 256, acc);
    const int tid = threadIdx.x, w = tid >> 6, l = tid & 63, g = l >> 4, lr = l & 15;
    unsigned short* ob = attn + (size_t)bc * 65536 + (size_t)(mt * 256 + w * 64) * 128;
#pragma unroll
    for (int i = 0; i < 4; ++i)
#pragma unroll
        for (int r = 0; r < 4; ++r) {
            float mx = -1e30f;
#pragma unroll
            for (int fj = 0; fj < 8; ++fj) mx = fmaxf(mx, acc[i][fj][r]);
#pragma unroll
            for (int d = 1; d < 16; d <<= 1) mx = fmaxf(mx, __shfl_xor(mx, d));
            float s = 0.f, e[8];
#pragma unroll
            for (int fj = 0; fj < 8; ++fj) { e[fj] = __expf(acc[i][fj][r] - mx); s += e[fj]; }
#pragma unroll
            for (int d = 1; d < 16; d <<= 1) s += __shfl_xor(s, d);
            const float inv = 1.f / s;
            const int row = i * 16 + g * 4 + r;
#pragma unroll
            for (int fj = 0; fj < 8; ++fj)
                ob[(size_t)row * 128 + fj * 16 + lr] = f2bf(e[fj] * inv);
        }
}

// vt[n][w] = sum_b v2t[n][b] * v1m[w][b]   (= (v1@v2)^T)
__global__ __launch_bounds__(256) void k_v(const unsigned short* __restrict__ v2t,
                                           const unsigned short* __restrict__ v1m,
                                           unsigned short* __restrict__ vt)
{
    const int bc = blockIdx.z, mt = blockIdx.y;
    f32x4 acc[4][4] = {};
    mmcore<2, 128>((const char*)(v2t + (size_t)bc * 65536 + (size_t)mt * 16384), 256,
                   (const char*)(v1m + (size_t)bc * 16384), 256, acc);
    unsigned short* out = vt + (size_t)bc * 65536 + (size_t)mt * 16384;
    const int tid = threadIdx.x, w = tid >> 6, l = tid & 63, g = l >> 4, lr = l & 15;
    const int wm = (w >> 1) * 64, wn = (w & 1) * 64;
#pragma unroll
    for (int i = 0; i < 4; ++i)
#pragma unroll
        for (int j = 0; j < 4; ++j)
#pragma unroll
            for (int r = 0; r < 4; ++r)
                out[(size_t)(wm + i * 16 + g * 4 + r) * 128 + wn + j * 16 + lr] = f2bf(acc[i][j][r]);
}

// out = x + attn@v (fp32 residual) + per-channel sum/sumsq atomics
__global__ __launch_bounds__(256) void k_y(const unsigned short* __restrict__ attn,
                                           const unsigned short* __restrict__ vt,
                                           const float* __restrict__ x,
                                           float* __restrict__ outp,
                                           float* __restrict__ stats)
{
    const int bc = blockIdx.z, c = bc & 15;
    const int my = blockIdx.y, nx = blockIdx.x;
    f32x4 acc[4][4] = {};
    mmcore<2, 128>((const char*)(attn + (size_t)bc * 65536 + (size_t)my * 16384), 256,
                   (const char*)(vt + (size_t)bc * 65536 + (size_t)nx * 16384), 256, acc);
    const float* xb = x + (size_t)bc * 262144;
    float* ob = outp + (size_t)bc * 262144;
    const int tid = threadIdx.x, w = tid >> 6, l = tid & 63, g = l >> 4, lr = l & 15;
    const int wm = (w >> 1) * 64, wn = (w & 1) * 64;
    float lsum = 0.f, lss = 0.f;
#pragma unroll
    for (int i = 0; i < 4; ++i)
#pragma unroll
        for (int j = 0; j < 4; ++j)
#pragma unroll
            for (int r = 0; r < 4; ++r) {
                const size_t off = (size_t)(my * 128 + wm + i * 16 + g * 4 + r) * 512
                                 + nx * 128 + wn + j * 16 + lr;
                const float yv = acc[i][j][r] + xb[off];
                ob[off] = yv;
                lsum += yv; lss += yv * yv;
            }
#pragma unroll
    for (int d = 32; d >= 1; d >>= 1) { lsum += __shfl_xor(lsum, d); lss += __shfl_xor(lss, d); }
    __shared__ float r1[4], r2[4];
    if (l == 0) { r1[w] = lsum; r2[w] = lss; }
    __syncthreads();
    if (tid == 0) {
        atomicAdd(&stats[c * 2 + 0], r1[0] + r1[1] + r1[2] + r1[3]);
        atomicAdd(&stats[c * 2 + 1], r2[0] + r2[1] + r2[2] + r2[3]);
    }
}

__global__ void k_fin(float* __restrict__ stats, const float* __restrict__ gamma,
                      const float* __restrict__ beta)
{
    const int c = threadIdx.x;
    if (c < 16) {
        const float cnt  = 2097152.f;             // 8*512*512
        const float mean = stats[c * 2 + 0] / cnt;
        const float var  = stats[c * 2 + 1] / cnt - mean * mean;
        const float sc   = rsqrtf(var + 1e-5f) * gamma[c];
        stats[32 + c * 2 + 0] = sc;
        stats[32 + c * 2 + 1] = beta[c] - mean * sc;
    }
}

__global__ __launch_bounds__(256) void k_norm(float* __restrict__ out,
                                              const float* __restrict__ stats)
{
    const long tot = 8388608;                     // 33.5M floats / 4
    for (long i = (long)blockIdx.x * blockDim.x + threadIdx.x; i < tot;
         i += (long)gridDim.x * blockDim.x) {
        const int c = (int)((i * 4) >> 18) & 15;
        const float sc = stats[32 + c * 2 + 0];
        const float sh = stats[32 + c * 2 + 1];
        float4 v = ((float4*)out)[i];
        v.x = v.x * sc + sh; v.y = v.y * sc + sh; v.z = v.z * sc + sh; v.w = v.w * sc + sh;
        ((float4*)out)[i] = v;
    }
}

extern "C" void kernel_launch(void* const* d_in, const int* in_sizes, int n_in,
                              void* d_out, int out_size, void* d_ws, size_t ws_size,
                              hipStream_t stream)
{
    (void)in_sizes; (void)n_in; (void)out_size; (void)ws_size;
    const float* x     = (const float*)d_in[0];
    const float* wq    = (const float*)d_in[1];
    const float* kl    = (const float*)d_in[2];
    const float* kr    = (const float*)d_in[3];
    const float* v1l   = (const float*)d_in[4];
    const float* v1r   = (const float*)d_in[5];
    const float* v2w   = (const float*)d_in[6];
    const float* gamma = (const float*)d_in[7];
    const float* beta  = (const float*)d_in[8];
    float* out = (float*)d_out;
    char*  ws  = (char*)d_ws;

    unsigned short* xb   = (unsigned short*)(ws + OB_XB);
    unsigned short* xt   = (unsigned short*)(ws + OB_XT);
    unsigned short* klb  = (unsigned short*)(ws + OB_KLB);
    unsigned short* v1lb = (unsigned short*)(ws + OB_V1LB);
    unsigned short* v2wb = (unsigned short*)(ws + OB_V2WB);
    unsigned short* wqt  = (unsigned short*)(ws + OB_WQT);
    unsigned short* krt  = (unsigned short*)(ws + OB_KRT);
    unsigned short* v1rt = (unsigned short*)(ws + OB_V1RT);
    unsigned short* bufb = (unsigned short*)(ws + OB_BUF);
    unsigned short* v2t  = (unsigned short*)(ws + OB_V2T);
    unsigned short* kmat = (unsigned short*)(ws + OB_KM);
    unsigned short* v1m  = (unsigned short*)(ws + OB_V1M);
    unsigned short* q    = (unsigned short*)(ws + OB_Q);
    unsigned short* attn = (unsigned short*)(ws + OB_ATT);
    unsigned short* vt   = (unsigned short*)(ws + OB_VT);
    float*          st   = (float*)(ws + OB_ST);

    hipLaunchKernelGGL(k_zero,  dim3(1), dim3(64), 0, stream, st);
    hipLaunchKernelGGL(kcvt,    dim3(1024), dim3(256), 0, stream, kl,  klb,  262144);
    hipLaunchKernelGGL(kcvt,    dim3(1024), dim3(256), 0, stream, v1l, v1lb, 262144);
    hipLaunchKernelGGL(kcvt,    dim3(1024), dim3(256), 0, stream, v2w, v2wb, 262144);
    hipLaunchKernelGGL(ktransx, dim3(8, 8, 128), dim3(256), 0, stream, x, xb, xt);
    hipLaunchKernelGGL(ktransw, dim3(2, 8, 16), dim3(256), 0, stream, wq,  wqt);
    hipLaunchKernelGGL(ktransw, dim3(2, 8, 16), dim3(256), 0, stream, kr,  krt);
    hipLaunchKernelGGL(ktransw, dim3(2, 8, 16), dim3(256), 0, stream, v1r, v1rt);
    hipLaunchKernelGGL(k_wx,    dim3(4, 3, 128), dim3(256), 0, stream, klb, v1lb, v2wb, xt, bufb, v2t);
    hipLaunchKernelGGL(k_kr,    dim3(1, 2, 128), dim3(256), 0, stream, bufb, krt, v1rt, kmat, v1m);
    hipLaunchKernelGGL(k_q,     dim3(1, 4, 128), dim3(256), 0, stream, xb, wqt, q);
    hipLaunchKernelGGL(k_at,    dim3(1, 2, 128), dim3(256), 0, stream, q, kmat, attn);
    hipLaunchKernelGGL(k_v,     dim3(1, 4, 128), dim3(256), 0, stream, v2t, v1m, vt);
    hipLaunchKernelGGL(k_y,     dim3(4, 4, 128), dim3(256), 0, stream, attn, vt, x, out, st);
    hipLaunchKernelGGL(k_fin,   dim3(1), dim3(64), 0, stream, st, gamma, beta);
    hipLaunchKernelGGL(k_norm,  dim3(2048), dim3(256), 0, stream, out, st);
}